// Round 3
// baseline (428.928 us; speedup 1.0000x reference)
//
#include <hip/hip_runtime.h>

#define NN 50000
#define NE 600000
#define DIM 128

typedef unsigned short u16;
typedef unsigned int u32;
typedef __attribute__((ext_vector_type(8))) short short8;
typedef __attribute__((ext_vector_type(4))) float floatx4;

__device__ __forceinline__ float bf2f(u16 u) { return __uint_as_float(((u32)u) << 16); }
__device__ __forceinline__ u16 f2bf(float f) {
    u32 x = __float_as_uint(f);
    return (u16)((x + 0x7FFFu + ((x >> 16) & 1u)) >> 16);  // RNE
}

// ---- dtype sniffers --------------------------------------------------------
// flags[0]=float tensors are f32 (vs bf16); flags[1]=always 0 (bf16 selector);
// flags[2]=edge_index is int64 (vs int32)
__global__ void k_sniff(const u16* __restrict__ xb, const int* __restrict__ ei,
                        int* __restrict__ flags) {
    __shared__ int cntf, cnti;
    if (threadIdx.x == 0) { cntf = 0; cnti = 0; }
    __syncthreads();
    int lf = 0, li = 0;
    // f32 stream misread as bf16 words: ~43% of words have exponent >= 0x91;
    // bf16 N(0,1) data: none.
    for (int i = threadIdx.x; i < 65536; i += 256) {
        u32 e = (xb[i] >> 7) & 0xFFu;
        lf += (e >= 0x91u) ? 1 : 0;
    }
    // int64 indices misread as int32: odd words are high halves == 0;
    // int32 indices: odd words are edge values, ~never 0.
    for (int i = threadIdx.x; i < 4096; i += 256) {
        li += (ei[2 * i + 1] != 0) ? 1 : 0;
    }
    if (lf) atomicAdd(&cntf, lf);
    if (li) atomicAdd(&cnti, li);
    __syncthreads();
    if (threadIdx.x == 0) {
        flags[0] = (cntf > 64) ? 1 : 0;
        flags[1] = 0;
        flags[2] = (cnti < 16) ? 1 : 0;
    }
}

__device__ __forceinline__ int ld_idx(const int* e, int i, int is64) {
    return is64 ? e[2 * i] : e[i];  // little-endian low half
}

// ---- CSR build -------------------------------------------------------------
__global__ void k_hist(const int* __restrict__ ei, const int* __restrict__ flags,
                       int* __restrict__ degi) {
    int i = blockIdx.x * 256 + threadIdx.x;
    if (i < NE) {
        int d = ld_idx(ei, NE + i, flags[2]);
        if ((u32)d < NN) atomicAdd(&degi[d], 1);
    }
}

__global__ void k_alloc(const int* __restrict__ degi, int* __restrict__ offs,
                        float* __restrict__ dinv, int* __restrict__ total) {
    int n = blockIdx.x * 256 + threadIdx.x;
    if (n < NN) {
        int c = degi[n];
        dinv[n] = rsqrtf((float)(c + 1));  // +1 self-loop; always > 0
        offs[n] = atomicAdd(total, c);
    }
}

__global__ void k_fill(const int* __restrict__ ei, const int* __restrict__ flags,
                       const int* __restrict__ offs, int* __restrict__ cur,
                       int* __restrict__ srclist) {
    int i = blockIdx.x * 256 + threadIdx.x;
    if (i < NE) {
        int is64 = flags[2];
        int d = ld_idx(ei, NE + i, is64);
        if ((u32)d >= NN) return;  // mirror k_hist guard exactly
        int p = atomicAdd(&cur[d], 1);
        int slot = offs[d] + p;
        if ((u32)slot < NE) srclist[slot] = ld_idx(ei, i, is64);
    }
}

// Wt[n][k] = W[k][n]; W read as f32 or bf16 per flag
__global__ void k_transpose(const void* __restrict__ W, u16* __restrict__ Wt,
                            const int* __restrict__ flags) {
    int isf = flags[0];
    for (int i = threadIdx.x; i < DIM * DIM; i += 256) {
        int k = i >> 7, n = i & 127;
        u16 v = isf ? f2bf(((const float*)W)[i]) : ((const u16*)W)[i];
        Wt[n * DIM + k] = v;
    }
}

// ---- aggregation: t[n] = dinv[n]*sum_s dinv[s]*feat[s] + dinv[n]^2*feat[n]
// one wave per node; feat dtype selected by fsel[0] (uniform branch); bf16 out
__global__ __launch_bounds__(256) void k_aggregate(
    const void* __restrict__ feat, const int* __restrict__ offs,
    const int* __restrict__ degi, const int* __restrict__ srclist,
    const float* __restrict__ dinv, const int* __restrict__ fsel,
    u16* __restrict__ outT) {
    int wave = (blockIdx.x * 256 + threadIdx.x) >> 6;
    int lane = threadIdx.x & 63;
    if (wave >= NN) return;
    int isf = fsel[0];
    int n = wave;
    int beg = offs[n], cnt = degi[n];
    // hard guards: wild values can only cause numeric error, never wild reads
    if (beg < 0 || beg > NE) { beg = 0; cnt = 0; }
    if (cnt < 0) cnt = 0;
    if (cnt > NE - beg) cnt = NE - beg;
    float dn = dinv[n];
    float a0 = 0.f, a1 = 0.f;
    if (isf) {
        const float* ff = (const float*)feat;
        for (int i = 0; i < cnt; ++i) {
            int s = srclist[beg + i];
            if ((u32)s >= NN) continue;
            float ds = dinv[s];
            float2 v = ((const float2*)(ff + (size_t)s * DIM))[lane];
            a0 += ds * v.x;
            a1 += ds * v.y;
        }
        float2 vs = ((const float2*)(ff + (size_t)n * DIM))[lane];
        a0 = dn * a0 + dn * dn * vs.x;
        a1 = dn * a1 + dn * dn * vs.y;
    } else {
        const u16* fb = (const u16*)feat;
        for (int i = 0; i < cnt; ++i) {
            int s = srclist[beg + i];
            if ((u32)s >= NN) continue;
            float ds = dinv[s];
            u32 u = ((const u32*)(fb + (size_t)s * DIM))[lane];  // 2 bf16/lane
            a0 += ds * __uint_as_float(u << 16);
            a1 += ds * __uint_as_float(u & 0xFFFF0000u);
        }
        u32 us = ((const u32*)(fb + (size_t)n * DIM))[lane];
        a0 = dn * a0 + dn * dn * __uint_as_float(us << 16);
        a1 = dn * a1 + dn * dn * __uint_as_float(us & 0xFFFF0000u);
    }
    u32 o = ((u32)f2bf(a1) << 16) | (u32)f2bf(a0);
    ((u32*)(outT + (size_t)n * DIM))[lane] = o;
}

// ---- GEMM 50000x128x128 bf16 MFMA, no LDS; fused bias+relu.
// A (bf16) and out are disjoint buffers. Output format per ofl[0]: f32 or bf16.
__global__ __launch_bounds__(256) void k_gemm(
    const u16* __restrict__ A, const u16* __restrict__ Bt,
    const void* __restrict__ bias, const int* __restrict__ bfl,
    void* __restrict__ out, const int* __restrict__ ofl) {
    int wave = (blockIdx.x * 256 + threadIdx.x) >> 6;
    int lane = threadIdx.x & 63;
    if (wave >= (NN >> 4)) return;  // 3125 waves x 16 rows
    int bisf = bfl[0], oisf = ofl[0];
    int row0 = wave << 4;
    int m = lane & 15;
    int kg = lane >> 4;  // 0..3
    floatx4 acc[8];
#pragma unroll
    for (int t = 0; t < 8; ++t) acc[t] = (floatx4){0.f, 0.f, 0.f, 0.f};
#pragma unroll
    for (int kk = 0; kk < 4; ++kk) {
        int k0 = kk * 32 + kg * 8;
        short8 a = *(const short8*)(A + (size_t)(row0 + m) * DIM + k0);
#pragma unroll
        for (int nt = 0; nt < 8; ++nt) {
            short8 b = *(const short8*)(Bt + (size_t)(nt * 16 + m) * DIM + k0);
            acc[nt] = __builtin_amdgcn_mfma_f32_16x16x32_bf16(a, b, acc[nt], 0, 0, 0);
        }
    }
#pragma unroll
    for (int nt = 0; nt < 8; ++nt) {
        int col = nt * 16 + m;
        float bv = bisf ? ((const float*)bias)[col] : bf2f(((const u16*)bias)[col]);
#pragma unroll
        for (int r = 0; r < 4; ++r) {
            int row = row0 + kg * 4 + r;  // C/D: col=lane&15, row=(lane>>4)*4+reg
            float v = acc[nt][r] + bv;
            v = v > 0.f ? v : 0.f;
            if (oisf) ((float*)out)[(size_t)row * DIM + col] = v;
            else      ((u16*)out)[(size_t)row * DIM + col] = f2bf(v);
        }
    }
}

extern "C" void kernel_launch(void* const* d_in, const int* in_sizes, int n_in,
                              void* d_out, int out_size, void* d_ws, size_t ws_size,
                              hipStream_t stream) {
    (void)in_sizes; (void)n_in; (void)out_size; (void)ws_size;
    const void* x  = d_in[0];
    const int*  ei = (const int*)d_in[1];
    const void* W1 = d_in[2];
    const void* b1 = d_in[3];
    const void* W2 = d_in[4];
    const void* b2 = d_in[5];
    char* ws = (char*)d_ws;

    // workspace layout (~16.1 MB total)
    int*   degi    = (int*)(ws + 0);         // 200704 B
    int*   cur     = (int*)(ws + 200704);    // 200704 B
    int*   total   = (int*)(ws + 401408);    // 16 B
    int*   flags   = (int*)(ws + 401424);    // [0]=is_f32 [1]=0 [2]=idx_is_i64
    int*   offs    = (int*)(ws + 401920);    // 200704 B
    float* dinv    = (float*)(ws + 602624);  // 200704 B
    int*   srclist = (int*)(ws + 803328);    // 2400256 B
    u16*   W1t     = (u16*)(ws + 3203584);   // 32768 B
    u16*   W2t     = (u16*)(ws + 3236352);   // 32768 B
    u16*   tbuf    = (u16*)(ws + 3269120);   // 12800000 B (Ahat*feat staging)

    // z1 (bf16, 12.8 MB) stages in d_out's front; GEMM-2 overwrites d_out f32.
    u16* z1 = (u16*)d_out;

    hipMemsetAsync(ws, 0, 401920, stream);  // degi + cur + total + flags

    k_sniff<<<1, 256, 0, stream>>>((const u16*)x, ei, flags);
    k_hist<<<(NE + 255) / 256, 256, 0, stream>>>(ei, flags, degi);
    k_alloc<<<(NN + 255) / 256, 256, 0, stream>>>(degi, offs, dinv, total);
    k_fill<<<(NE + 255) / 256, 256, 0, stream>>>(ei, flags, offs, cur, srclist);
    k_transpose<<<1, 256, 0, stream>>>(W1, W1t, flags);
    k_transpose<<<1, 256, 0, stream>>>(W2, W2t, flags);

    // layer 1: t = Ahat*x (bf16, ws), z1 = relu(t@W1+b1) (bf16, in d_out front)
    k_aggregate<<<NN / 4, 256, 0, stream>>>(x, offs, degi, srclist, dinv, flags, tbuf);
    k_gemm<<<(3125 + 3) / 4, 256, 0, stream>>>(tbuf, W1t, b1, flags, z1, flags + 1);
    // layer 2: t = Ahat*z1 (bf16, ws), out = relu(t@W2+b2) — format per flag
    k_aggregate<<<NN / 4, 256, 0, stream>>>(z1, offs, degi, srclist, dinv, flags + 1, tbuf);
    k_gemm<<<(3125 + 3) / 4, 256, 0, stream>>>(tbuf, W2t, b2, flags, d_out, flags);
}

// Round 4
// 295.049 us; speedup vs baseline: 1.4538x; 1.4538x over previous
//
#include <hip/hip_runtime.h>

#define NN 50000
#define NE 600000
#define DIM 128

typedef unsigned short u16;
typedef unsigned int u32;
typedef __attribute__((ext_vector_type(8))) short short8;
typedef __attribute__((ext_vector_type(4))) float floatx4;

__device__ __forceinline__ float bflo(u32 u) { return __uint_as_float(u << 16); }
__device__ __forceinline__ float bfhi(u32 u) { return __uint_as_float(u & 0xFFFF0000u); }
__device__ __forceinline__ u16 f2bf(float f) {
    u32 x = __float_as_uint(f);
    return (u16)((x + 0x7FFFu + ((x >> 16) & 1u)) >> 16);  // RNE
}

// ---- index-width sniff: flags[3] = #nonzero odd int32 words in sample.
// int32 edges: odd words are real indices (~all nonzero). int64: high halves == 0.
__global__ void k_sniff_idx(const int* __restrict__ ei, int* __restrict__ flags) {
    int i = blockIdx.x * 256 + threadIdx.x;
    int local = 0;
    for (int k = i; k < 65536; k += 16 * 256) local += (ei[2 * k + 1] != 0) ? 1 : 0;
    if (local) atomicAdd(&flags[3], local);
}

__device__ __forceinline__ int ld_idx(const int* e, int i, int is64) {
    return is64 ? e[2 * i] : e[i];  // little-endian low half
}

// ---- CSR build -------------------------------------------------------------
__global__ void k_hist(const int* __restrict__ ei, const int* __restrict__ flags,
                       int* __restrict__ degi) {
    int is64 = (flags[3] < 1024) ? 1 : 0;
    int i = blockIdx.x * 256 + threadIdx.x;
    if (i < NE) {
        int d = ld_idx(ei, NE + i, is64);
        if ((u32)d < NN) atomicAdd(&degi[d], 1);
    }
}

__global__ void k_alloc(const int* __restrict__ degi, int* __restrict__ offs,
                        float* __restrict__ dinv, int* __restrict__ total) {
    int n = blockIdx.x * 256 + threadIdx.x;
    if (n < NN) {
        int c = degi[n];
        dinv[n] = rsqrtf((float)(c + 1));  // +1 self-loop; always > 0
        offs[n] = atomicAdd(total, c);
    }
}

__global__ void k_fill(const int* __restrict__ ei, const int* __restrict__ flags,
                       const int* __restrict__ offs, int* __restrict__ cur,
                       int* __restrict__ srclist) {
    int is64 = (flags[3] < 1024) ? 1 : 0;
    int i = blockIdx.x * 256 + threadIdx.x;
    if (i < NE) {
        int d = ld_idx(ei, NE + i, is64);
        if ((u32)d >= NN) return;  // mirror k_hist guard exactly
        int p = atomicAdd(&cur[d], 1);
        int slot = offs[d] + p;
        if ((u32)slot < NE) srclist[slot] = ld_idx(ei, i, is64);
    }
}

// ---- y = bf16(dinv[row] * x), 2 elems/thread ------------------------------
__global__ void k_scale(const float* __restrict__ x, const float* __restrict__ dinv,
                        u32* __restrict__ y) {
    int i = blockIdx.x * 256 + threadIdx.x;  // over NN*DIM/2 float2
    if (i >= NN * DIM / 2) return;
    float dn = dinv[i >> 6];
    float2 v = ((const float2*)x)[i];
    y[i] = ((u32)f2bf(dn * v.y) << 16) | (u32)f2bf(dn * v.x);
}

// ---- both weight transposes in one dispatch (128 blocks) -------------------
__global__ void k_transW(const float* __restrict__ W1, const float* __restrict__ W2,
                         u16* __restrict__ W1t, u16* __restrict__ W2t) {
    int b = blockIdx.x;
    const float* W = (b < 64) ? W1 : W2;
    u16* Wt = (b < 64) ? W1t : W2t;
    int e = (b & 63) * 256 + threadIdx.x;
    int k = e >> 7, n = e & 127;
    Wt[n * DIM + k] = f2bf(W[e]);
}

// ---- aggregation: t[n] = dn * (y[n] + sum_s y[s]); rows = 64 u32 (bf16x2)
// one wave/node; depth-3 row pipeline + idx prefetch; branchless clamps
__global__ __launch_bounds__(256) void k_agg(
    const u32* __restrict__ y, const int* __restrict__ offs,
    const int* __restrict__ degi, const int* __restrict__ srclist,
    const float* __restrict__ dinv, u32* __restrict__ t) {
    int wave = __builtin_amdgcn_readfirstlane((int)((blockIdx.x * 256 + threadIdx.x) >> 6));
    int lane = threadIdx.x & 63;
    if (wave >= NN) return;
    int n = wave;
    int beg = offs[n], cnt = degi[n];
    if (beg < 0 || beg > NE) { beg = 0; cnt = 0; }
    if (cnt < 0) cnt = 0;
    if (cnt > NE - beg) cnt = NE - beg;
    float dn = dinv[n];
    u32 us = y[(size_t)n * 64 + lane];  // self term (y already dinv-scaled)
    float a0 = bflo(us), a1 = bfhi(us);
    if (cnt > 0) {
        int c1 = cnt - 1;
        int j1 = 1 < c1 ? 1 : c1, j2 = 2 < c1 ? 2 : c1;
        int s0 = srclist[beg], s1 = srclist[beg + j1], s2 = srclist[beg + j2];
        s0 = ((u32)s0 < NN) ? s0 : 0;
        s1 = ((u32)s1 < NN) ? s1 : 0;
        s2 = ((u32)s2 < NN) ? s2 : 0;
        u32 u0 = y[(size_t)s0 * 64 + lane];
        u32 u1 = y[(size_t)s1 * 64 + lane];
        for (int i = 0; i < cnt; ++i) {
            int nx = i + 3; nx = nx < c1 ? nx : c1;    // idx prefetch (clamped)
            int s3 = srclist[beg + nx];
            s3 = ((u32)s3 < NN) ? s3 : 0;
            u32 u2 = y[(size_t)s2 * 64 + lane];        // row prefetch depth-3
            a0 += bflo(u0); a1 += bfhi(u0);            // consume oldest
            u0 = u1; u1 = u2; s2 = s3;
        }
    }
    t[(size_t)n * 64 + lane] = ((u32)f2bf(dn * a1) << 16) | (u32)f2bf(dn * a0);
}

// ---- GEMM 50000x128x128 bf16 MFMA, no LDS; fused bias+relu epilogue.
// mode 0: store bf16 of dinv[row]*relu(v)  (layer-1 -> pre-scaled z1)
// mode 1: store f32 of relu(v)             (layer-2 -> final output)
__global__ __launch_bounds__(256) void k_gemm(
    const u16* A, const u16* __restrict__ Bt, const float* __restrict__ bias,
    const float* __restrict__ dinv, void* out, int mode) {
    int wave = (blockIdx.x * 256 + threadIdx.x) >> 6;
    int lane = threadIdx.x & 63;
    if (wave >= (NN >> 4)) return;  // 3125 waves x 16 rows
    int row0 = wave << 4;
    int m = lane & 15;
    int kg = lane >> 4;  // 0..3
    floatx4 acc[8];
#pragma unroll
    for (int t = 0; t < 8; ++t) acc[t] = (floatx4){0.f, 0.f, 0.f, 0.f};
#pragma unroll
    for (int kk = 0; kk < 4; ++kk) {
        int k0 = kk * 32 + kg * 8;
        short8 a = *(const short8*)(A + (size_t)(row0 + m) * DIM + k0);
#pragma unroll
        for (int nt = 0; nt < 8; ++nt) {
            short8 b = *(const short8*)(Bt + (size_t)(nt * 16 + m) * DIM + k0);
            acc[nt] = __builtin_amdgcn_mfma_f32_16x16x32_bf16(a, b, acc[nt], 0, 0, 0);
        }
    }
    float4 d4 = (mode == 0) ? *(const float4*)(dinv + row0 + kg * 4)
                            : make_float4(1.f, 1.f, 1.f, 1.f);
#pragma unroll
    for (int nt = 0; nt < 8; ++nt) {
        int col = nt * 16 + m;
        float bv = bias[col];
#pragma unroll
        for (int r = 0; r < 4; ++r) {
            int row = row0 + kg * 4 + r;  // C/D: col=lane&15, row=(lane>>4)*4+reg
            float v = acc[nt][r] + bv;
            v = v > 0.f ? v : 0.f;
            if (mode == 0)
                ((u16*)out)[(size_t)row * DIM + col] = f2bf(v * (&d4.x)[r]);
            else
                ((float*)out)[(size_t)row * DIM + col] = v;
        }
    }
}

extern "C" void kernel_launch(void* const* d_in, const int* in_sizes, int n_in,
                              void* d_out, int out_size, void* d_ws, size_t ws_size,
                              hipStream_t stream) {
    (void)in_sizes; (void)n_in; (void)out_size; (void)ws_size;
    const float* x  = (const float*)d_in[0];
    const int*   ei = (const int*)d_in[1];
    const float* W1 = (const float*)d_in[2];
    const float* b1 = (const float*)d_in[3];
    const float* W2 = (const float*)d_in[4];
    const float* b2 = (const float*)d_in[5];
    char* ws = (char*)d_ws;

    // workspace layout (16.07 MB, same footprint as the known-good round 3)
    int*   degi    = (int*)(ws + 0);         // 200704 B
    int*   cur     = (int*)(ws + 200704);    // 200704 B
    int*   total   = (int*)(ws + 401408);    // 16 B
    int*   flags   = (int*)(ws + 401424);    // flags[3] = idx sniff count
    int*   offs    = (int*)(ws + 401920);    // 200704 B
    float* dinv    = (float*)(ws + 602624);  // 200704 B
    int*   srclist = (int*)(ws + 803328);    // 2400256 B
    u16*   W1t     = (u16*)(ws + 3203584);   // 32768 B
    u16*   W2t     = (u16*)(ws + 3236352);   // 32768 B
    u32*   ybuf    = (u32*)(ws + 3269120);   // 12800000 B: y1, then t2

    // d_out (25.6 MB f32) staging: z1s bf16 in lower half, t1 bf16 in upper half
    u16* out16 = (u16*)d_out;
    u16* z1s = out16;            // [0, 12.8 MB)
    u16* t1  = out16 + 6400000;  // [12.8, 25.6 MB)

    hipMemsetAsync(ws, 0, 401440, stream);  // degi + cur + total + flags

    k_sniff_idx<<<16, 256, 0, stream>>>(ei, flags);
    k_hist<<<(NE + 255) / 256, 256, 0, stream>>>(ei, flags, degi);
    k_alloc<<<(NN + 255) / 256, 256, 0, stream>>>(degi, offs, dinv, total);
    k_fill<<<(NE + 255) / 256, 256, 0, stream>>>(ei, flags, offs, cur, srclist);
    k_scale<<<NN * DIM / 2 / 256, 256, 0, stream>>>(x, dinv, ybuf);
    k_transW<<<128, 256, 0, stream>>>(W1, W2, W1t, W2t);

    // layer 1: t1 = dn*(sum y1 + y1_self); z1s = dinv*relu(t1@W1+b1) (bf16)
    k_agg<<<NN / 4, 256, 0, stream>>>(ybuf, offs, degi, srclist, dinv, (u32*)t1);
    k_gemm<<<(3125 + 3) / 4, 256, 0, stream>>>(t1, W1t, b1, dinv, z1s, 0);
    // layer 2: t2 = dn*(sum z1s + z1s_self) (into ws); out = relu(t2@W2+b2) f32
    k_agg<<<NN / 4, 256, 0, stream>>>((const u32*)z1s, offs, degi, srclist, dinv, ybuf);
    k_gemm<<<(3125 + 3) / 4, 256, 0, stream>>>((const u16*)ybuf, W2t, b2, dinv, d_out, 1);
}